// Round 14
// baseline (1060.088 us; speedup 1.0000x reference)
//
#include <hip/hip_runtime.h>
#include <stdint.h>

typedef __bf16 bf16;
typedef bf16 bf16x8 __attribute__((ext_vector_type(8)));
typedef bf16 bf16x4 __attribute__((ext_vector_type(4)));
typedef float f32x4 __attribute__((ext_vector_type(4)));
typedef uint32_t u32;
typedef uint8_t u8;

#define B_TOT 16384
#define SWG 8
#define NWGS (B_TOT / SWG)   // 2048

__device__ __forceinline__ f32x4 mfma32(bf16x8 a, bf16x8 b, f32x4 c) {
  return __builtin_amdgcn_mfma_f32_16x16x32_bf16(a, b, c, 0, 0, 0);
}
__device__ __forceinline__ bf16x8 zero8() {
  bf16x8 v;
#pragma unroll
  for (int j = 0; j < 8; j++) v[j] = (bf16)0.f;
  return v;
}

// ---- slot barriers ----
__device__ __forceinline__ void bar_lg() {
  __builtin_amdgcn_sched_barrier(0);
  asm volatile("s_waitcnt lgkmcnt(0)" ::: "memory");
  __builtin_amdgcn_s_barrier();
  __builtin_amdgcn_sched_barrier(0);
}
__device__ __forceinline__ void bar_v0() {
  __builtin_amdgcn_sched_barrier(0);
  asm volatile("s_waitcnt vmcnt(0) lgkmcnt(0)" ::: "memory");
  __builtin_amdgcn_s_barrier();
  __builtin_amdgcn_sched_barrier(0);
}

// Stage a full [128 rows x 256 bytes] weight tile (32KB) into LDS.
// Swizzle on GLOBAL source (byte ^ ((row&7)<<4)); LDS image linear.
// Issued at slot START so latency hides under the slot's compute (T14).
__device__ __forceinline__ void stage32(const u8* __restrict__ src, int rowstride, int colbase,
                                        u8* dst, int tid) {
  __builtin_amdgcn_sched_barrier(0);
#pragma unroll
  for (int rr = 0; rr < 4; ++rr) {
    u32 o = (u32)(rr * 512 + tid) * 16u;
    u32 row = o >> 8, cb = o & 0xF0u;
    const u8* s = src + (size_t)row * (size_t)rowstride + (size_t)colbase
                      + (size_t)(cb ^ ((row & 7u) << 4));
    __builtin_amdgcn_global_load_lds((const __attribute__((address_space(1))) u32*)s,
                                     (__attribute__((address_space(3))) u32*)(dst + o),
                                     16, 0, 0);
  }
  __builtin_amdgcn_sched_barrier(0);
}

// weight fragment from a 32KB full stage ([128 rows][256B], swizzled)
__device__ __forceinline__ bf16x8 wread32(const u8* Wb, int row, u32 koff) {
  return *(const bf16x8*)(Wb + (u32)(row * 256) + (koff ^ (((u32)row & 7u) << 4)));
}

// scalar store into swizzled row-major [64 rows][128 cols] bf16 ACTIVATION tile
__device__ __forceinline__ void st_row(u8* base, int row, int col, bf16 v) {
  *(bf16*)(base + (u32)(row * 256) + (u32)((2 * col) ^ ((row & 15) << 4))) = v;
}

// acc[4 samples][2 nt] += A (rows s*16+node, full K=128, from act tile) @ W.
// A-frags loaded per-ks (transient, 16 regs) so peak pressure stays < 128.
__device__ __forceinline__ void gemm_q(const u8* Wb, const u8* Ta, f32x4 acc[4][2],
                                       int qn, int g, int c) {
  const u32 swA = (u32)c << 4;
#pragma unroll
  for (int ks = 0; ks < 4; ++ks) {
    bf16x8 a[4];
#pragma unroll
    for (int s = 0; s < 4; ++s)
      a[s] = *(const bf16x8*)(Ta + (u32)((s * 16 + c) * 256)
                                 + (((u32)(ks * 64 + g * 16)) ^ swA));
#pragma unroll
    for (int nt = 0; nt < 2; ++nt) {
      bf16x8 b = wread32(Wb, qn * 32 + nt * 16 + c, (u32)(ks * 64 + g * 16));
#pragma unroll
      for (int s = 0; s < 4; ++s)
        acc[s][nt] = mfma32(a[s], b, acc[s][nt]);
    }
  }
}

// epilogue -> swizzled row-major tile, scalar stores
template <bool RELU>
__device__ __forceinline__ void epi_q(const f32x4 acc[4][2], const float* __restrict__ bias,
                                      u8* Rdst, int qn, int g, int c) {
#pragma unroll
  for (int nt = 0; nt < 2; ++nt) {
    int col = qn * 32 + nt * 16 + c;
    float bb = bias[col];
#pragma unroll
    for (int s = 0; s < 4; ++s)
#pragma unroll
      for (int r = 0; r < 4; ++r) {
        float v = acc[s][nt][r] + bb;
        if (RELU) v = fmaxf(v, 0.f);
        st_row(Rdst, s * 16 + 4 * g + r, col, (bf16)v);
      }
  }
}

// pack 4 f32 -> two u32 of bf16 pairs
__device__ __forceinline__ void pack4(const f32x4 v, u32& w0, u32& w1) {
  union { bf16 h[2]; u32 u; } t0, t1;
  t0.h[0] = (bf16)v[0]; t0.h[1] = (bf16)v[1];
  t1.h[0] = (bf16)v[2]; t1.h[1] = (bf16)v[3];
  w0 = t0.u; w1 = t1.u;
}

// C-frag of 16x16 block T -> A/B-frag of T^T (r6-verified); zeros for g>=2
__device__ __forceinline__ bf16x8 Rfrag(u32 w0, u32 w1, int g, int c) {
  int s0 = 32 * g + c;
  int s1 = 32 * g + 16 + c;
  u32 a0 = (u32)__shfl((int)w0, s0);
  u32 a1 = (u32)__shfl((int)w1, s0);
  u32 a2 = (u32)__shfl((int)w0, s1);
  u32 a3 = (u32)__shfl((int)w1, s1);
  union { u32 u[4]; bf16x8 v; } r;
  bool ok = (g < 2);
  r.u[0] = ok ? a0 : 0u; r.u[1] = ok ? a1 : 0u;
  r.u[2] = ok ? a2 : 0u; r.u[3] = ok ? a3 : 0u;
  return r.v;
}

__device__ __forceinline__ void ln_part4(const f32x4 x[4][2], float sS[4][4], float sS2[4][4]) {
#pragma unroll
  for (int s = 0; s < 4; ++s) {
    f32x4 a = x[s][0] + x[s][1];
    f32x4 b = x[s][0] * x[s][0] + x[s][1] * x[s][1];
#pragma unroll
    for (int r = 0; r < 4; ++r) {
      float u = a[r], u2 = b[r];
#pragma unroll
      for (int off = 1; off < 16; off <<= 1) { u += __shfl_xor(u, off); u2 += __shfl_xor(u2, off); }
      sS[s][r] = u; sS2[s][r] = u2;
    }
  }
}

__global__ void __launch_bounds__(512, 2)
bot_main(const int* __restrict__ adj,
         const float* __restrict__ embB, const float* __restrict__ posE,
         const float* __restrict__ pbq, const float* __restrict__ pbk,
         const float* __restrict__ pbv, const float* __restrict__ pbo,
         const float* __restrict__ l1g, const float* __restrict__ l1b,
         const float* __restrict__ l2g, const float* __restrict__ l2b,
         const float* __restrict__ pb1, const float* __restrict__ pb2,
         const bf16* __restrict__ feats, const bf16* __restrict__ embWT,
         const bf16* __restrict__ wqT, const bf16* __restrict__ wkT,
         const bf16* __restrict__ wvT, const bf16* __restrict__ woT,
         const bf16* __restrict__ w1T, const bf16* __restrict__ w2T,
         float* __restrict__ out) {
  __shared__ u8 smem[163840];   // 96KB acts (2 pairs x 3x16KB) + 2x32KB weights
  const int tid = threadIdx.x;
  const int w = tid >> 6, lane = tid & 63, g = lane >> 4, c = lane & 15;
  const int p = w >> 2, qn = w & 3;   // pair (0..1, 4 samples each), N-quarter (0..3)
  const int S0 = blockIdx.x * SWG;

  u8* pairb = smem + p * 49152;
  u8* Th = pairb;            // h -> h2   ([64 rows][128 cols] swizzled)
  u8* Tq = pairb + 16384;    // q -> O -> U
  u8* Tk = pairb + 32768;    // k; LN scratch at base in dead windows
  u8* WA = smem + 98304;     // 32KB weight buffer A (Wq, Wv, W1cX)
  u8* WB = smem + 131072;    // 32KB weight buffer B (Wk, Wo, W2cX)
  float* scr = (float*)Tk;   // [64 rows][4 quarters][2]

  // transposed mask for swapped-QK^T S^T layout: lane(g,c),r -> (key m=4g+r, query n=c)
  float maskT[4];
#pragma unroll
  for (int r = 0; r < 4; ++r) {
    int m = 4 * g + r;
    maskT[r] = (adj[c * 16 + m] != 0 || c == m) ? 0.f : -1e9f;
  }

  // ---------------- embed (WG-cooperative, transient x0 over act area) ----------------
  {
    float* x0 = (float*)smem;  // [8 samples][2048] = 64KB
    bf16x8 af[2];
#pragma unroll
    for (int ks = 0; ks < 2; ++ks)
      af[ks] = *(const bf16x8*)(feats + (size_t)(S0 + (c & 7)) * 64 + ks * 32 + g * 8);
    f32x4 ea[16] = {};
#pragma unroll
    for (int nt = 0; nt < 16; ++nt)
#pragma unroll
      for (int ks = 0; ks < 2; ++ks) {
        bf16x8 bw = *(const bf16x8*)(embWT + (size_t)(w * 256 + nt * 16 + c) * 64 + ks * 32 + g * 8);
        ea[nt] = mfma32(af[ks], bw, ea[nt]);
      }
    if (g < 2) {
#pragma unroll
      for (int nt = 0; nt < 16; ++nt)
#pragma unroll
        for (int r = 0; r < 4; ++r)
          x0[(4 * g + r) * 2048 + w * 256 + nt * 16 + c] = ea[nt][r];
    }
  }
  __syncthreads();

  f32x4 x[4][2];
  {
    const float* x0 = (const float*)smem;
#pragma unroll
    for (int nt = 0; nt < 2; ++nt)
#pragma unroll
      for (int r = 0; r < 4; ++r) {
        int n = 4 * g + r, d = qn * 32 + nt * 16 + c;
        float eb = embB[n * 128 + d] + posE[n * 128 + d];
#pragma unroll
        for (int s = 0; s < 4; ++s)
          x[s][nt][r] = x0[(4 * p + s) * 2048 + n * 128 + d] + eb;
      }
  }
  __syncthreads();

  // ---------------- layers: 15 full-weight slots, issue-early lag-1 ----------------
#pragma unroll 1
  for (int l = 0; l < 4; ++l) {
    const u8* Wq_l = (const u8*)(wqT + (size_t)l * 16384);
    const u8* Wk_l = (const u8*)(wkT + (size_t)l * 16384);
    const u8* Wv_l = (const u8*)(wvT + (size_t)l * 16384);
    const u8* Wo_l = (const u8*)(woT + (size_t)l * 16384);
    const u8* W1_l = (const u8*)(w1T + (size_t)l * 65536);
    const u8* W2_l = (const u8*)(w2T + (size_t)l * 65536);

    float sS[4][4], sS2[4][4], mean[4][4], rstd[4][4];
    const f32x4 zz = {0.f, 0.f, 0.f, 0.f};

    // s0: LN1 partials -> scr (Tk base; k dead from prev layer)
    ln_part4(x, sS, sS2);
    if (c == 0) {
#pragma unroll
      for (int s = 0; s < 4; ++s)
#pragma unroll
        for (int r = 0; r < 4; ++r) {
          int row = s * 16 + 4 * g + r;
          scr[(row * 4 + qn) * 2 + 0] = sS[s][r];
          scr[(row * 4 + qn) * 2 + 1] = sS2[s][r];
        }
    }
    bar_lg();

    // s1: issue Wq->WA | LN1 combine + h -> Th
    stage32(Wq_l, 256, 0, WA, tid);
#pragma unroll
    for (int s = 0; s < 4; ++s)
#pragma unroll
      for (int r = 0; r < 4; ++r) {
        int row = s * 16 + 4 * g + r;
        float u = 0.f, u2 = 0.f;
#pragma unroll
        for (int qq = 0; qq < 4; ++qq) {
          u += scr[(row * 4 + qq) * 2 + 0];
          u2 += scr[(row * 4 + qq) * 2 + 1];
        }
        float mu = u * (1.f / 128.f);
        float va = u2 * (1.f / 128.f) - mu * mu;
        mean[s][r] = mu; rstd[s][r] = rsqrtf(va + 1e-5f);
      }
#pragma unroll
    for (int nt = 0; nt < 2; ++nt) {
      int col = qn * 32 + nt * 16 + c;
      float gg = l1g[l * 128 + col], bb = l1b[l * 128 + col];
#pragma unroll
      for (int s = 0; s < 4; ++s)
#pragma unroll
        for (int r = 0; r < 4; ++r)
          st_row(Th, s * 16 + 4 * g + r, col,
                 (bf16)((x[s][nt][r] - mean[s][r]) * rstd[s][r] * gg + bb));
    }
    bar_v0();

    f32x4 acc[4][2];
    // s2: issue Wk->WB | Q gemm (WA, A=h) + q epi -> Tq
    stage32(Wk_l, 256, 0, WB, tid);
#pragma unroll
    for (int s = 0; s < 4; ++s)
#pragma unroll
      for (int nt = 0; nt < 2; ++nt) acc[s][nt] = zz;
    gemm_q(WA, Th, acc, qn, g, c);
    epi_q<false>(acc, pbq + l * 128, Tq, qn, g, c);
    bar_v0();

    // s3: issue Wv->WA | K gemm (WB, A=h) + k epi -> Tk
    stage32(Wv_l, 256, 0, WA, tid);
#pragma unroll
    for (int s = 0; s < 4; ++s)
#pragma unroll
      for (int nt = 0; nt < 2; ++nt) acc[s][nt] = zz;
    gemm_q(WB, Th, acc, qn, g, c);
    epi_q<false>(acc, pbk + l * 128, Tk, qn, g, c);
    bar_v0();

    // s4: issue Wo->WB | V gemm (WA, A=h) -> Vf; ATTENTION (2 heads x 4 samples); O -> Tq
    stage32(Wo_l, 256, 0, WB, tid);
    {
      bf16x8 Vf[4][2];
#pragma unroll
      for (int s = 0; s < 4; ++s)
#pragma unroll
        for (int nt = 0; nt < 2; ++nt) acc[s][nt] = zz;
      gemm_q(WA, Th, acc, qn, g, c);
#pragma unroll
      for (int nt = 0; nt < 2; ++nt) {
        float bb = pbv[l * 128 + qn * 32 + nt * 16 + c];
#pragma unroll
        for (int s = 0; s < 4; ++s) {
          f32x4 v;
#pragma unroll
          for (int r = 0; r < 4; ++r) v[r] = acc[s][nt][r] + bb;
          u32 w0, w1; pack4(v, w0, w1);
          Vf[s][nt] = Rfrag(w0, w1, g, c);
        }
      }
      const u32 swa = (u32)c << 4;
#pragma unroll
      for (int hh = 0; hh < 2; ++hh) {
        const int gh = qn * 2 + hh;
#pragma unroll
        for (int s = 0; s < 4; ++s) {
          bf16x8 qf, kf;
          if (g < 2) {
            qf = *(const bf16x8*)(Tq + (u32)((s * 16 + c) * 256)
                                     + (((u32)(gh * 32 + g * 16)) ^ swa));
            kf = *(const bf16x8*)(Tk + (u32)((s * 16 + c) * 256)
                                     + (((u32)(gh * 32 + g * 16)) ^ swa));
          } else { qf = zero8(); kf = zero8(); }
          f32x4 st = mfma32(kf, qf, zz);    // S^T
          float pr[4];
#pragma unroll
          for (int r = 0; r < 4; ++r) pr[r] = st[r] * 0.25f + maskT[r];
          float mx = fmaxf(fmaxf(pr[0], pr[1]), fmaxf(pr[2], pr[3]));
          mx = fmaxf(mx, __shfl_xor(mx, 16));
          mx = fmaxf(mx, __shfl_xor(mx, 32));
          float sm = 0.f;
#pragma unroll
          for (int r = 0; r < 4; ++r) { pr[r] = __expf(pr[r] - mx); sm += pr[r]; }
          sm += __shfl_xor(sm, 16);
          sm += __shfl_xor(sm, 32);
          float pinv = __fdividef(1.f, sm);
          f32x4 pv;
#pragma unroll
          for (int r = 0; r < 4; ++r) pv[r] = pr[r] * pinv;
          u32 w0, w1; pack4(pv, w0, w1);
          bf16x8 Pf = Rfrag(w0, w1, g, c);
          f32x4 oo = mfma32(Vf[s][hh], Pf, zz);    // O^T
          pack4(oo, w0, w1);
          bf16x8 Of = Rfrag(w0, w1, g, c);
          if (g < 2)
            *(bf16x8*)(Tq + (u32)((s * 16 + c) * 256)
                          + (((u32)(gh * 32 + g * 16)) ^ swa)) = Of;
        }
      }
    }
    bar_v0();

    // s5: (no issue) | O-proj (WB, A=O) into x; +bo; LN2 partials -> scr
    gemm_q(WB, Tq, x, qn, g, c);
#pragma unroll
    for (int nt = 0; nt < 2; ++nt) {
      float bb = pbo[l * 128 + qn * 32 + nt * 16 + c];
#pragma unroll
      for (int s = 0; s < 4; ++s)
#pragma unroll
        for (int r = 0; r < 4; ++r) x[s][nt][r] += bb;
    }
    ln_part4(x, sS, sS2);
    if (c == 0) {
#pragma unroll
      for (int s = 0; s < 4; ++s)
#pragma unroll
        for (int r = 0; r < 4; ++r) {
          int row = s * 16 + 4 * g + r;
          scr[(row * 4 + qn) * 2 + 0] = sS[s][r];
          scr[(row * 4 + qn) * 2 + 1] = sS2[s][r];
        }
    }
    bar_lg();

    // s6: issue W1c0->WA | LN2 combine + h2 -> Th
    stage32(W1_l, 256, 0, WA, tid);
#pragma unroll
    for (int s = 0; s < 4; ++s)
#pragma unroll
      for (int r = 0; r < 4; ++r) {
        int row = s * 16 + 4 * g + r;
        float u = 0.f, u2 = 0.f;
#pragma unroll
        for (int qq = 0; qq < 4; ++qq) {
          u += scr[(row * 4 + qq) * 2 + 0];
          u2 += scr[(row * 4 + qq) * 2 + 1];
        }
        float mu = u * (1.f / 128.f);
        float va = u2 * (1.f / 128.f) - mu * mu;
        mean[s][r] = mu; rstd[s][r] = rsqrtf(va + 1e-5f);
      }
#pragma unroll
    for (int nt = 0; nt < 2; ++nt) {
      int col = qn * 32 + nt * 16 + c;
      float gg = l2g[l * 128 + col], bb = l2b[l * 128 + col];
#pragma unroll
      for (int s = 0; s < 4; ++s)
#pragma unroll
        for (int r = 0; r < 4; ++r)
          st_row(Th, s * 16 + 4 * g + r, col,
                 (bf16)((x[s][nt][r] - mean[s][r]) * rstd[s][r] * gg + bb));
    }
    bar_v0();

    // ---------------- FFN: 2 slots per fc ----------------
#pragma unroll 1
    for (int fc = 0; fc < 4; ++fc) {
      // sU: issue W2c(fc)->WB | U gemm (WA, A=h2) + relu epi -> Tq
      stage32(W2_l, 1024, fc * 256, WB, tid);
      f32x4 uacc[4][2];
#pragma unroll
      for (int s = 0; s < 4; ++s)
#pragma unroll
        for (int nt = 0; nt < 2; ++nt) uacc[s][nt] = zz;
      gemm_q(WA, Th, uacc, qn, g, c);
      epi_q<true>(uacc, pb1 + l * 512 + fc * 128, Tq, qn, g, c);
      bar_v0();
      // sY: issue W1c(fc+1)->WA (fc<3) | Y gemm (WB, A=U) into x
      if (fc < 3) stage32(W1_l + (fc + 1) * 32768, 256, 0, WA, tid);
      gemm_q(WB, Tq, x, qn, g, c);
      if (fc < 3) bar_v0();
      else {
#pragma unroll
        for (int nt = 0; nt < 2; ++nt) {
          float bb = pb2[l * 128 + qn * 32 + nt * 16 + c];
#pragma unroll
          for (int s = 0; s < 4; ++s)
#pragma unroll
            for (int r = 0; r < 4; ++r) x[s][nt][r] += bb;
        }
        bar_lg();
      }
    }
  }

  // ---------------- output: LDS bounce -> coalesced nontemporal fp32 stores ----------------
#pragma unroll
  for (int nt = 0; nt < 2; ++nt) {
    int col = qn * 32 + nt * 16 + c;
#pragma unroll
    for (int s = 0; s < 4; ++s)
      *(f32x4*)(smem + (4 * p + s) * 8192 + col * 64 + g * 16) = x[s][nt];
  }
  bar_lg();
  {
    const int smp = S0 + w;          // wave w streams sample w
    const u8* src = smem + w * 8192;
#pragma unroll
    for (int it = 0; it < 8; ++it) {
      int n = it * 2 + (lane >> 5);
      int slot = lane & 31;
      f32x4 v;
#pragma unroll
      for (int e = 0; e < 4; ++e)
        v[e] = *(const float*)(src + (u32)((slot * 4 + e) * 64 + n * 4));
      __builtin_nontemporal_store(v, (f32x4*)(out + (size_t)smp * 2048 + n * 128 + slot * 4));
    }
  }
}

// ---------------- prep kernels ----------------
__global__ void prep_feats_k(const float* __restrict__ pos, const float* __restrict__ vel,
                             bf16* __restrict__ feats) {
  int i = blockIdx.x * 256 + threadIdx.x;
  if (i >= B_TOT * 64) return;
  int b = i >> 6, k = i & 63;
  float v = (k < 32) ? pos[b * 32 + k] : vel[b * 32 + (k - 32)];
  feats[i] = (bf16)v;
}

// dst[m][cc][rr] = (bf16) src[m][rr][cc]; src is [mats][R][C] fp32
__global__ void prep_tr_k(const float* __restrict__ src, bf16* __restrict__ dst,
                          int R, int C, int total) {
  int i = blockIdx.x * 256 + threadIdx.x;
  if (i >= total) return;
  int rc = R * C;
  int m = i / rc, rem = i % rc;
  int cc = rem / R, rr = rem % R;
  dst[i] = (bf16)src[(size_t)m * rc + rr * C + cc];
}

extern "C" void kernel_launch(void* const* d_in, const int* in_sizes, int n_in,
                              void* d_out, int out_size, void* d_ws, size_t ws_size,
                              hipStream_t stream) {
  const float* jp  = (const float*)d_in[0];
  const float* jv  = (const float*)d_in[1];
  const int*   adj = (const int*)d_in[2];
  const float* eW  = (const float*)d_in[3];
  const float* eB  = (const float*)d_in[4];
  const float* pE  = (const float*)d_in[5];
  const float* Wq  = (const float*)d_in[6];  const float* bq = (const float*)d_in[7];
  const float* Wk  = (const float*)d_in[8];  const float* bk = (const float*)d_in[9];
  const float* Wv  = (const float*)d_in[10]; const float* bv = (const float*)d_in[11];
  const float* Wo  = (const float*)d_in[12]; const float* bo = (const float*)d_in[13];
  const float* g1  = (const float*)d_in[14]; const float* be1 = (const float*)d_in[15];
  const float* g2  = (const float*)d_in[16]; const float* be2 = (const float*)d_in[17];
  const float* W1  = (const float*)d_in[18]; const float* b1 = (const float*)d_in[19];
  const float* W2  = (const float*)d_in[20]; const float* b2 = (const float*)d_in[21];

  bf16* ws    = (bf16*)d_ws;
  bf16* feats = ws;                    // 1048576
  bf16* embWT = ws + 1048576;          // 131072  [16*128 outcol][64 in]
  bf16* wqT   = embWT + 131072;        // 65536   [4][128 out][128 in]
  bf16* wkT   = wqT + 65536;
  bf16* wvT   = wkT + 65536;
  bf16* woT   = wvT + 65536;
  bf16* w1T   = woT + 65536;           // 262144  [4][512 f][128 in]
  bf16* w2T   = w1T + 262144;          // 262144  [4][128 out][512 f]

  prep_feats_k<<<(B_TOT * 64 + 255) / 256, 256, 0, stream>>>(jp, jv, feats);
  prep_tr_k<<<512, 256, 0, stream>>>(eW, embWT, 64, 128, 131072);
  prep_tr_k<<<256, 256, 0, stream>>>(Wq, wqT, 128, 128, 65536);
  prep_tr_k<<<256, 256, 0, stream>>>(Wk, wkT, 128, 128, 65536);
  prep_tr_k<<<256, 256, 0, stream>>>(Wv, wvT, 128, 128, 65536);
  prep_tr_k<<<256, 256, 0, stream>>>(Wo, woT, 128, 128, 65536);
  prep_tr_k<<<1024, 256, 0, stream>>>(W1, w1T, 128, 512, 262144);
  prep_tr_k<<<1024, 256, 0, stream>>>(W2, w2T, 512, 128, 262144);

  bot_main<<<NWGS, 512, 0, stream>>>(adj, eB, pE, bq, bk, bv, bo,
                                     g1, be1, g2, be2, b1, b2,
                                     feats, embWT, wqT, wkT, wvT, woT, w1T, w2T,
                                     (float*)d_out);
}